// Round 7
// baseline (569.004 us; speedup 1.0000x reference)
//
#include <hip/hip_runtime.h>
#include <hip/hip_fp16.h>
#include <math.h>

#define BB 4
#define HH 480
#define WW 640
#define HW (HH * WW)
#define PP (BB * HW)   // 1,228,800 pixels; PP % 256 == 0 (4800 blocks)

// Bilinear corner load with zero padding (precompute only)
__device__ __forceinline__ float ldz(const float* __restrict__ img, int y, int x) {
    bool v = ((unsigned)y < (unsigned)HH) & ((unsigned)x < (unsigned)WW);
    int off = v ? (y * WW + x) : 0;
    float val = img[off];
    return v ? val : 0.0f;
}

// Axis mapping for zero-padded bilinear on a clamped 2x2 square:
// contribution along this axis == s * [(1-t)*I[c0] + t*I[c0+1]], c0 in [0, H-2].
__device__ __forceinline__ void axis_map(int y0, float wy, int H,
                                         int& c0, float& t, float& s) {
    if (y0 >= 0 && y0 <= H - 2)      { c0 = y0;    t = wy;   s = 1.0f; }
    else if (y0 == -1)               { c0 = 0;     t = 0.0f; s = wy; }
    else if (y0 == H - 1)            { c0 = H - 2; t = 1.0f; s = 1.0f - wy; }
    else                             { c0 = 0;     t = 0.0f; s = 0.0f; }
}

// fast tanh: 1 - 2/(exp(2x)+1); __expf is v_exp-based (~1e-5 rel err, saturates correctly)
__device__ __forceinline__ float tanh_fast(float x) {
    return 1.0f - 2.0f / (__expf(2.0f * x) + 1.0f);
}

// ---------------------------------------------------------------------------
// Kernel 0: transpose weights [c=24][ci=8][k=9] -> wT[k=9][ci=8][c=24]
// (wT lives in bufA's storage — dead until prop iter 0 overwrites it)
// ---------------------------------------------------------------------------
__global__ void transpose_w_kernel(const float* __restrict__ w_oa, float* __restrict__ wT) {
    for (int i = threadIdx.x; i < 1728; i += 256) {
        const int k = i / 192;
        const int r = i - k * 192;
        const int ci = r / 24;
        const int c = r - ci * 24;
        wT[i] = w_oa[c * 72 + ci * 9 + k];
    }
}

// ---------------------------------------------------------------------------
// Kernel 1: per-pixel precompute (round-6 math; restructured conv).
// All 72 guidance taps are hoisted to registers first, then one fully
// unrolled 1728-FMA stream with wave-uniform (scalar) weight loads the
// compiler can prefetch far ahead — removes the per-kidx SMEM stall that
// held VALUBusy at 67%.  g[72]+acc[24] ~ 115 VGPR, capped at 128 by
// __launch_bounds__(256,4).
// Output per tap j (8 B): u32{ base19<<13 | aff13 }, u32{ half2(ty,tx) }
// plus explicit affC (center weight, pre-scaled by 8192).
// ---------------------------------------------------------------------------
__global__ __launch_bounds__(256, 4) void precompute_kernel(
    const float* __restrict__ guidance,
    const float* __restrict__ confidence,
    const float* __restrict__ wT,
    const float* __restrict__ b_oa,
    const float* __restrict__ aff_scale,
    uint4* __restrict__ PK4,
    float* __restrict__ affC)
{
    const int p = blockIdx.x * 256 + threadIdx.x;
    const int b = p / HW;
    const int rem = p - b * HW;
    const int y = rem / WW;
    const int x = rem - y * WW;

    const float* gb = guidance + (size_t)b * 8 * HW;

    // ---- hoist all 9x8 guidance taps into registers (coalesced loads) ----
    float g[72];
    #pragma unroll
    for (int kidx = 0; kidx < 9; ++kidx) {
        const int yy = y + kidx / 3 - 1;
        const int xx = x + kidx % 3 - 1;
        const bool valid = ((unsigned)yy < (unsigned)HH) & ((unsigned)xx < (unsigned)WW);
        const int base = valid ? (yy * WW + xx) : 0;
        #pragma unroll
        for (int ci = 0; ci < 8; ++ci) {
            float v = gb[ci * HW + base];
            g[kidx * 8 + ci] = valid ? v : 0.0f;
        }
    }

    // ---- single unrolled FMA stream; weights via scalar loads ----
    float acc[24];
    #pragma unroll
    for (int c = 0; c < 24; ++c) acc[c] = b_oa[c];

    #pragma unroll
    for (int k = 0; k < 72; ++k) {
        const float gv = g[k];
        #pragma unroll
        for (int c = 0; c < 24; ++c)
            acc[c] = fmaf(gv, wT[k * 24 + c], acc[c]);
    }

    // --- affinity head ---
    const float inv_scale = 1.0f / (aff_scale[0] + 1e-8f);
    const float* cb = confidence + (size_t)b * HW;
    const float fy = (float)y, fx = (float)x;

    float affv[8];
    #pragma unroll
    for (int j = 0; j < 8; ++j) {
        const float oy = acc[j], ox = acc[8 + j];
        const float a = tanh_fast(acc[16 + j]) * inv_scale;
        const float ysj = fy + oy, xsj = fx + ox;   // conf sampled at p+off (no tap)
        const float y0f = floorf(ysj), x0f = floorf(xsj);
        const float wy = ysj - y0f, wx = xsj - x0f;
        const int y0 = (int)y0f, x0 = (int)x0f;
        const float v00 = ldz(cb, y0, x0),     v01 = ldz(cb, y0, x0 + 1);
        const float v10 = ldz(cb, y0 + 1, x0), v11 = ldz(cb, y0 + 1, x0 + 1);
        const float conf = v00 * (1.0f - wy) * (1.0f - wx) + v01 * (1.0f - wy) * wx
                         + v10 * wy * (1.0f - wx)          + v11 * wy * wx;
        affv[j] = a * conf;
    }

    float s = 1e-4f;
    #pragma unroll
    for (int j = 0; j < 8; ++j) s += fabsf(affv[j]);
    s = fmaxf(s, 1.0f);
    const float inv_s = 1.0f / s;
    float sum = 0.0f;
    #pragma unroll
    for (int j = 0; j < 8; ++j) { affv[j] *= inv_s; sum += affv[j]; }
    const float aref = 1.0f - sum;

    float m = aref;
    #pragma unroll
    for (int j = 0; j < 8; ++j) m = fmaxf(m, affv[j]);
    float e[8];
    float denom = 0.0f;
    #pragma unroll
    for (int j = 0; j < 8; ++j) { e[j] = __expf(affv[j] - m); denom += e[j]; }
    const float ec = __expf(aref - m);
    denom += ec;
    const float invden = 1.0f / denom;

    affC[p] = ec * invden * 8192.0f;   // pre-scaled center weight

    unsigned ba[8], tt[8];
    #pragma unroll
    for (int j = 0; j < 8; ++j) {
        const int t9 = (j < 4) ? j : j + 1;          // 9-tap index (skip center 4)
        const float khv = (float)(t9 / 3 - 1);
        const float kwv = (float)(t9 % 3 - 1);
        const float ys = (fy + khv) + acc[j];
        const float xs = (fx + kwv) + acc[8 + j];
        const float y0f = floorf(ys), x0f = floorf(xs);
        const float wy = ys - y0f, wx = xs - x0f;
        int y0c, x0c; float ty, tx, sy, sx;
        axis_map((int)y0f, wy, HH, y0c, ty, sy);
        axis_map((int)x0f, wx, WW, x0c, tx, sx);

        const float aeff = (e[j] * invden) * sy * sx;           // in [0,1)
        unsigned aq = __float2uint_rn(aeff * 8192.0f);
        aq = aq > 8191u ? 8191u : aq;
        ba[j] = ((unsigned)(y0c * WW + x0c) << 13) | aq;
        __half2 h2 = __floats2half2_rn(ty, tx);                 // low = ty, high = tx
        tt[j] = __builtin_bit_cast(unsigned, h2);
    }
    PK4[4 * p + 0] = make_uint4(ba[0], tt[0], ba[1], tt[1]);
    PK4[4 * p + 1] = make_uint4(ba[2], tt[2], ba[3], tt[3]);
    PK4[4 * p + 2] = make_uint4(ba[4], tt[4], ba[5], tt[5]);
    PK4[4 * p + 3] = make_uint4(ba[6], tt[6], ba[7], tt[7]);
}

// ---------------------------------------------------------------------------
// Kernel 2: one propagation step. 18 launches, ping-pong buffers.
// UNCHANGED from round 6 (passing) — this round collects its counters.
// Streams per pixel: 64 B PK4 + 4 B affC + 4 B src + 4 B write.
// ---------------------------------------------------------------------------
__global__ __launch_bounds__(256) void prop_kernel(
    const float* __restrict__ src,
    float* __restrict__ dst,
    const uint4* __restrict__ PK4,
    const float* __restrict__ affC)
{
    const int p = blockIdx.x * 256 + threadIdx.x;
    const int b = p / HW;
    const float* fb = src + (size_t)b * HW;

    const uint4 q0 = PK4[4 * p + 0];
    const uint4 q1 = PK4[4 * p + 1];
    const uint4 q2 = PK4[4 * p + 2];
    const uint4 q3 = PK4[4 * p + 3];

    float acc = 0.0f;

    auto tap = [&](unsigned bav, unsigned tw) {
        const float af = (float)(bav & 8191u);
        const float* g = fb + (bav >> 13);
        const float2 top2 = *reinterpret_cast<const float2*>(g);
        const float2 bot2 = *reinterpret_cast<const float2*>(g + WW);
        const float2 t = __half22float2(__builtin_bit_cast(__half2, tw)); // (ty, tx)
        const float top = fmaf(t.y, top2.y - top2.x, top2.x);
        const float bot = fmaf(t.y, bot2.y - bot2.x, bot2.x);
        acc = fmaf(af, fmaf(t.x, bot - top, top), acc);
    };
    tap(q0.x, q0.y); tap(q0.z, q0.w);
    tap(q1.x, q1.y); tap(q1.z, q1.w);
    tap(q2.x, q2.y); tap(q2.z, q2.w);
    tap(q3.x, q3.y); tap(q3.z, q3.w);

    dst[p] = fmaf(affC[p], src[p], acc) * (1.0f / 8192.0f);
}

extern "C" void kernel_launch(void* const* d_in, const int* in_sizes, int n_in,
                              void* d_out, int out_size, void* d_ws, size_t ws_size,
                              hipStream_t stream) {
    const float* feat_init  = (const float*)d_in[0];
    const float* guidance   = (const float*)d_in[1];
    const float* confidence = (const float*)d_in[2];
    const float* w_oa       = (const float*)d_in[3];
    const float* b_oa       = (const float*)d_in[4];
    const float* aff_scale  = (const float*)d_in[5];
    float* out = (float*)d_out;
    float* ws  = (float*)d_ws;

    // ws layout (floats): PK4[16P] | affC[P] | bufA[P]
    // wT (1728 floats) aliases bufA: dead once precompute has read it,
    // before prop iter 0 writes bufA (stream-ordered).
    const size_t need = (size_t)18 * PP * sizeof(float);
    if (ws_size < need) return;  // fail visibly rather than corrupt

    uint4* PK4  = reinterpret_cast<uint4*>(ws);
    float* affC = ws + (size_t)16 * PP;
    float* bufA = ws + (size_t)17 * PP;
    float* wT   = bufA;

    const int grid = PP / 256;
    transpose_w_kernel<<<1, 256, 0, stream>>>(w_oa, wT);
    precompute_kernel<<<grid, 256, 0, stream>>>(guidance, confidence, wT, b_oa,
                                                aff_scale, PK4, affC);

    // ping-pong: even iters -> bufA, odd iters -> d_out (iter 17 -> d_out)
    const float* src = feat_init;
    for (int i = 0; i < 18; ++i) {
        float* dst = (i & 1) ? out : bufA;
        prop_kernel<<<grid, 256, 0, stream>>>(src, dst, PK4, affC);
        src = dst;
    }
}

// Round 8
// 563.227 us; speedup vs baseline: 1.0103x; 1.0103x over previous
//
#include <hip/hip_runtime.h>
#include <hip/hip_fp16.h>
#include <math.h>

#define BB 4
#define HH 480
#define WW 640
#define HW (HH * WW)
#define PP (BB * HW)   // 1,228,800 pixels

// tile geometry for prop: 64x4 pixels, halo 8 cols / 4 rows each side
#define TW 64
#define TH 4
#define CWID 80      // TW + 16
#define RHGT 12      // TH + 8
#define TPB (HH/TH * WW/TW)   // tiles per image = 120*10 = 1200

// Bilinear corner load with zero padding (precompute only)
__device__ __forceinline__ float ldz(const float* __restrict__ img, int y, int x) {
    bool v = ((unsigned)y < (unsigned)HH) & ((unsigned)x < (unsigned)WW);
    int off = v ? (y * WW + x) : 0;
    float val = img[off];
    return v ? val : 0.0f;
}

// Axis mapping for zero-padded bilinear on a clamped 2x2 square:
// contribution along this axis == s * [(1-t)*I[c0] + t*I[c0+1]], c0 in [0, H-2].
__device__ __forceinline__ void axis_map(int y0, float wy, int H,
                                         int& c0, float& t, float& s) {
    if (y0 >= 0 && y0 <= H - 2)      { c0 = y0;    t = wy;   s = 1.0f; }
    else if (y0 == -1)               { c0 = 0;     t = 0.0f; s = wy; }
    else if (y0 == H - 1)            { c0 = H - 2; t = 1.0f; s = 1.0f - wy; }
    else                             { c0 = 0;     t = 0.0f; s = 0.0f; }
}

// fast tanh: 1 - 2/(exp(2x)+1)
__device__ __forceinline__ float tanh_fast(float x) {
    return 1.0f - 2.0f / (__expf(2.0f * x) + 1.0f);
}

// ---------------------------------------------------------------------------
// Kernel 0: transpose weights [c=24][ci=8][k=9] -> wT[k=9][ci=8][c=24]
// ---------------------------------------------------------------------------
__global__ void transpose_w_kernel(const float* __restrict__ w_oa, float* __restrict__ wT) {
    for (int i = threadIdx.x; i < 1728; i += 256) {
        const int k = i / 192;
        const int r = i - k * 192;
        const int ci = r / 24;
        const int c = r - ci * 24;
        wT[i] = w_oa[c * 72 + ci * 9 + k];
    }
}

// ---------------------------------------------------------------------------
// Kernel 1: per-pixel precompute (round-6 structure + fast transcendentals).
// Per tap j (8 B): u32{ (y0c<<10|x0c) << 13 | aff13 }, u32{ half2(ty,tx) }
// aff13 includes the zero-pad scale sy*sx. affC = center weight * 8192.
// ---------------------------------------------------------------------------
__global__ __launch_bounds__(256) void precompute_kernel(
    const float* __restrict__ guidance,
    const float* __restrict__ confidence,
    const float* __restrict__ wT,
    const float* __restrict__ b_oa,
    const float* __restrict__ aff_scale,
    uint4* __restrict__ PK4,
    float* __restrict__ affC)
{
    const int p = blockIdx.x * 256 + threadIdx.x;
    const int b = p / HW;
    const int rem = p - b * HW;
    const int y = rem / WW;
    const int x = rem - y * WW;

    float acc[24];
    #pragma unroll
    for (int c = 0; c < 24; ++c) acc[c] = b_oa[c];   // uniform -> s_load

    const float* gb = guidance + (size_t)b * 8 * HW;

    #pragma unroll 1
    for (int kidx = 0; kidx < 9; ++kidx) {
        const int yy = y + kidx / 3 - 1;
        const int xx = x + kidx % 3 - 1;
        const bool valid = ((unsigned)yy < (unsigned)HH) & ((unsigned)xx < (unsigned)WW);
        const int base = valid ? (yy * WW + xx) : 0;
        float g[8];
        #pragma unroll
        for (int ci = 0; ci < 8; ++ci) {
            float v = gb[ci * HW + base];
            g[ci] = valid ? v : 0.0f;
        }
        const float* wk = wT + kidx * 192;   // uniform address -> scalar loads
        #pragma unroll
        for (int ci = 0; ci < 8; ++ci) {
            const float gv = g[ci];
            #pragma unroll
            for (int c = 0; c < 24; ++c)
                acc[c] = fmaf(gv, wk[ci * 24 + c], acc[c]);
        }
    }

    // --- affinity head ---
    const float inv_scale = 1.0f / (aff_scale[0] + 1e-8f);
    const float* cb = confidence + (size_t)b * HW;
    const float fy = (float)y, fx = (float)x;

    float affv[8];
    #pragma unroll
    for (int j = 0; j < 8; ++j) {
        const float oy = acc[j], ox = acc[8 + j];
        const float a = tanh_fast(acc[16 + j]) * inv_scale;
        const float ysj = fy + oy, xsj = fx + ox;
        const float y0f = floorf(ysj), x0f = floorf(xsj);
        const float wy = ysj - y0f, wx = xsj - x0f;
        const int y0 = (int)y0f, x0 = (int)x0f;
        const float v00 = ldz(cb, y0, x0),     v01 = ldz(cb, y0, x0 + 1);
        const float v10 = ldz(cb, y0 + 1, x0), v11 = ldz(cb, y0 + 1, x0 + 1);
        const float conf = v00 * (1.0f - wy) * (1.0f - wx) + v01 * (1.0f - wy) * wx
                         + v10 * wy * (1.0f - wx)          + v11 * wy * wx;
        affv[j] = a * conf;
    }

    float s = 1e-4f;
    #pragma unroll
    for (int j = 0; j < 8; ++j) s += fabsf(affv[j]);
    s = fmaxf(s, 1.0f);
    const float inv_s = 1.0f / s;
    float sum = 0.0f;
    #pragma unroll
    for (int j = 0; j < 8; ++j) { affv[j] *= inv_s; sum += affv[j]; }
    const float aref = 1.0f - sum;

    float m = aref;
    #pragma unroll
    for (int j = 0; j < 8; ++j) m = fmaxf(m, affv[j]);
    float e[8];
    float denom = 0.0f;
    #pragma unroll
    for (int j = 0; j < 8; ++j) { e[j] = __expf(affv[j] - m); denom += e[j]; }
    const float ec = __expf(aref - m);
    denom += ec;
    const float invden = 1.0f / denom;

    affC[p] = ec * invden * 8192.0f;   // pre-scaled center weight

    unsigned ba[8], tt[8];
    #pragma unroll
    for (int j = 0; j < 8; ++j) {
        const int t9 = (j < 4) ? j : j + 1;          // 9-tap index (skip center 4)
        const float khv = (float)(t9 / 3 - 1);
        const float kwv = (float)(t9 % 3 - 1);
        const float ys = (fy + khv) + acc[j];
        const float xs = (fx + kwv) + acc[8 + j];
        const float y0f = floorf(ys), x0f = floorf(xs);
        const float wy = ys - y0f, wx = xs - x0f;
        int y0c, x0c; float ty, tx, sy, sx;
        axis_map((int)y0f, wy, HH, y0c, ty, sy);
        axis_map((int)x0f, wx, WW, x0c, tx, sx);

        const float aeff = (e[j] * invden) * sy * sx;           // in [0,1)
        unsigned aq = __float2uint_rn(aeff * 8192.0f);
        aq = aq > 8191u ? 8191u : aq;
        ba[j] = ((((unsigned)y0c << 10) | (unsigned)x0c) << 13) | aq;
        __half2 h2 = __floats2half2_rn(ty, tx);                 // low = ty, high = tx
        tt[j] = __builtin_bit_cast(unsigned, h2);
    }
    PK4[4 * p + 0] = make_uint4(ba[0], tt[0], ba[1], tt[1]);
    PK4[4 * p + 1] = make_uint4(ba[2], tt[2], ba[3], tt[3]);
    PK4[4 * p + 2] = make_uint4(ba[4], tt[4], ba[5], tt[5]);
    PK4[4 * p + 3] = make_uint4(ba[6], tt[6], ba[7], tt[7]);
}

// ---------------------------------------------------------------------------
// Kernel 2: one propagation step, LDS-tiled gathers.
// Block = 64x4 pixel tile; stages a 12x80 src halo tile (3.8 KB) with
// coalesced loads, then taps read 2x2 quads from LDS (in-tile with
// P~0.999 given offset std ~0.85 px). Rare out-of-tile taps fall back to
// exec-masked global float2 loads (branch skipped when execz).
// ---------------------------------------------------------------------------
__global__ __launch_bounds__(256) void prop_kernel(
    const float* __restrict__ src,
    float* __restrict__ dst,
    const uint4* __restrict__ PK4,
    const float* __restrict__ affC)
{
    __shared__ float tile[RHGT * CWID];

    const int tid = threadIdx.x;
    const int blk = blockIdx.x;
    const int b = blk / TPB;
    const int r = blk - b * TPB;
    const int ty0 = (r / (WW / TW)) * TH;
    const int tx0 = (r - (r / (WW / TW)) * (WW / TW)) * TW;
    const int ry0 = ty0 - 4;
    const int cx0 = tx0 - 8;

    const float* fb = src + (size_t)b * HW;

    // ---- stage halo tile (in-image cells only; others never read) ----
    #pragma unroll
    for (int i = 0; i < 4; ++i) {
        const int idx = tid + i * 256;
        if (idx < RHGT * CWID) {
            const int rr = idx / CWID;
            const int cc = idx - rr * CWID;
            const int gy = ry0 + rr, gx = cx0 + cc;
            if (((unsigned)gy < (unsigned)HH) & ((unsigned)gx < (unsigned)WW))
                tile[idx] = fb[gy * WW + gx];
        }
    }
    __syncthreads();

    const int lx = tid & 63, ly = tid >> 6;
    const int y = ty0 + ly, x = tx0 + lx;
    const int p = b * HW + y * WW + x;

    const uint4 q0 = PK4[4 * p + 0];
    const uint4 q1 = PK4[4 * p + 1];
    const uint4 q2 = PK4[4 * p + 2];
    const uint4 q3 = PK4[4 * p + 3];

    // center tap from LDS
    float acc = affC[p] * tile[(ly + 4) * CWID + lx + 8];

    const int base_off = ry0 * CWID + cx0;   // lidx = y0c*CWID + x0c - base_off

    auto tap = [&](unsigned bav, unsigned tw) {
        const float af = (float)(bav & 8191u);
        const int y0c = (int)(bav >> 23);
        const int x0c = (int)((bav >> 13) & 1023u);
        float v00, v01, v10, v11;
        const bool in = ((unsigned)(y0c - ry0) < (unsigned)(RHGT - 1)) &
                        ((unsigned)(x0c - cx0) < (unsigned)(CWID - 1));
        if (__builtin_expect(in, 1)) {
            const int l = y0c * CWID + x0c - base_off;
            v00 = tile[l];          v01 = tile[l + 1];
            v10 = tile[l + CWID];   v11 = tile[l + CWID + 1];
        } else {
            const float* g = fb + (y0c * WW + x0c);
            const float2 t2 = *reinterpret_cast<const float2*>(g);
            const float2 b2 = *reinterpret_cast<const float2*>(g + WW);
            v00 = t2.x; v01 = t2.y; v10 = b2.x; v11 = b2.y;
        }
        const float2 t = __half22float2(__builtin_bit_cast(__half2, tw)); // (ty, tx)
        const float top = fmaf(t.y, v01 - v00, v00);
        const float bot = fmaf(t.y, v11 - v10, v10);
        acc = fmaf(af, fmaf(t.x, bot - top, top), acc);
    };
    tap(q0.x, q0.y); tap(q0.z, q0.w);
    tap(q1.x, q1.y); tap(q1.z, q1.w);
    tap(q2.x, q2.y); tap(q2.z, q2.w);
    tap(q3.x, q3.y); tap(q3.z, q3.w);

    dst[p] = acc * (1.0f / 8192.0f);
}

extern "C" void kernel_launch(void* const* d_in, const int* in_sizes, int n_in,
                              void* d_out, int out_size, void* d_ws, size_t ws_size,
                              hipStream_t stream) {
    const float* feat_init  = (const float*)d_in[0];
    const float* guidance   = (const float*)d_in[1];
    const float* confidence = (const float*)d_in[2];
    const float* w_oa       = (const float*)d_in[3];
    const float* b_oa       = (const float*)d_in[4];
    const float* aff_scale  = (const float*)d_in[5];
    float* out = (float*)d_out;
    float* ws  = (float*)d_ws;

    // ws layout (floats): PK4[16P] | affC[P] | bufA[P]; wT aliases bufA
    const size_t need = (size_t)18 * PP * sizeof(float);
    if (ws_size < need) return;  // fail visibly rather than corrupt

    uint4* PK4  = reinterpret_cast<uint4*>(ws);
    float* affC = ws + (size_t)16 * PP;
    float* bufA = ws + (size_t)17 * PP;
    float* wT   = bufA;

    const int grid = PP / 256;
    transpose_w_kernel<<<1, 256, 0, stream>>>(w_oa, wT);
    precompute_kernel<<<grid, 256, 0, stream>>>(guidance, confidence, wT, b_oa,
                                                aff_scale, PK4, affC);

    // ping-pong: even iters -> bufA, odd iters -> d_out (iter 17 -> d_out)
    const float* srcp = feat_init;
    for (int i = 0; i < 18; ++i) {
        float* dstp = (i & 1) ? out : bufA;
        prop_kernel<<<grid, 256, 0, stream>>>(srcp, dstp, PK4, affC);
        srcp = dstp;
    }
}